// Round 1
// baseline (1388.657 us; speedup 1.0000x reference)
//
#include <hip/hip_runtime.h>
#include <stdint.h>

typedef __bf16 bf16;
typedef __attribute__((ext_vector_type(8))) __bf16 bf16x8;
typedef __attribute__((ext_vector_type(4))) float f32x4;
typedef __attribute__((ext_vector_type(4))) unsigned int u32x4;

typedef __attribute__((address_space(1))) unsigned gas_u32;
typedef __attribute__((address_space(3))) unsigned las_u32;

__device__ __forceinline__ unsigned short f2b_bits(float f) {
    unsigned u = __builtin_bit_cast(unsigned, f);
    u += 0x7fffu + ((u >> 16) & 1u);   // RNE
    return (unsigned short)(u >> 16);
}
__device__ __forceinline__ bf16 f2b(float f) { return __builtin_bit_cast(bf16, f2b_bits(f)); }
__device__ __forceinline__ float lo16f(unsigned u) { return __builtin_bit_cast(float, u << 16); }
__device__ __forceinline__ float hi16f(unsigned u) { return __builtin_bit_cast(float, u & 0xffff0000u); }

// async global->LDS, 16B per lane; LDS dest is wave-uniform base (+lane*16 by HW)
__device__ __forceinline__ void gl2lds16(const void* g, void* l) {
    __builtin_amdgcn_global_load_lds((gas_u32*)(uintptr_t)g, (las_u32*)(uintptr_t)l, 16, 0, 0);
}

#define BM 128
#define BN 128
#define BK 32

// AMODE: 0 = A bf16 [M x lda]; 1 = A = concat(cc,cr) fp32 (K=2048, per-half lda=1024), async fp32
//            staging + cvt at frag-read; 2 = A bf16 gathered: row r -> Ap row rowidx[r] (Ap2 = int*)
// ACT:   0 none, 1 leaky-relu(0.2), 2 clip(-1,1)
// OMODE: 0 = bf16 out [M x N]; 1 = fp32 split (N=1024): col<512 -> Op, col>=512 -> Op2, ldc=512
template<int AMODE, int ACT, int OMODE>
__global__ __launch_bounds__(256, 2)
void gemm_k(const void* __restrict__ Ap, const void* __restrict__ Ap2,
            const bf16* __restrict__ Bt, const float* __restrict__ bias,
            void* __restrict__ Op, void* __restrict__ Op2,
            int M, int N, int K, int lda)
{
    // AMODE==1 stores the A tile as raw fp32 (16 KB); else bf16 (8 KB)
    constexpr int ASZ = (AMODE == 1) ? (BM * BK * 2) : (BM * BK);
    __shared__ __align__(16) bf16 As[ASZ];
    __shared__ __align__(16) bf16 Bs[BN * BK];
    float* Asf = (float*)As;

    const int tid  = threadIdx.x;
    const int wave = tid >> 6;
    const int lane = tid & 63;
    const int quad = lane >> 4;
    const int l16  = lane & 15;
    const int bm0 = blockIdx.y * BM;
    const int bn0 = blockIdx.x * BN;
    const int wm0 = (wave >> 1) << 6;
    const int wn0 = (wave & 1) << 6;

    f32x4 acc[4][4];
#pragma unroll
    for (int a = 0; a < 4; a++)
#pragma unroll
        for (int c = 0; c < 4; c++) acc[a][c] = {0.f, 0.f, 0.f, 0.f};

    // hoisted staging pointers
    const bf16* aptr[2];
    const float* asrc0[4];   // cc half, swizzled column group
    const float* asrc1[4];   // cr half
    if constexpr (AMODE == 1) {
#pragma unroll
        for (int j = 0; j < 4; j++) {
            const int s2 = j * 256 + tid;
            const int arow = s2 >> 3, kq = s2 & 7;
            const int kgrp = kq ^ (arow & 7);     // XOR swizzle (bank spread at frag read)
            asrc0[j] = (const float*)Ap  + (size_t)(bm0 + arow) * 1024 + kgrp * 4;
            asrc1[j] = (const float*)Ap2 + (size_t)(bm0 + arow) * 1024 + kgrp * 4;
        }
    } else {
#pragma unroll
        for (int i = 0; i < 2; i++) {
            const int s = i * 256 + tid;
            const int arow = s >> 2, kp = s & 3;
            size_t rbase;
            if constexpr (AMODE == 2) rbase = (size_t)((const int*)Ap2)[bm0 + arow] * (size_t)lda;
            else                      rbase = (size_t)(bm0 + arow) * (size_t)lda;
            aptr[i] = (const bf16*)Ap + rbase + kp * 8;
        }
    }
    const bf16* bptr[2];
#pragma unroll
    for (int i = 0; i < 2; i++) {
        const int s = i * 256 + tid;
        const int brow = s >> 2, kp = s & 3;
        bptr[i] = Bt + (size_t)(bn0 + brow) * (size_t)K + kp * 8;
    }

    for (int k0 = 0; k0 < K; k0 += BK) {
        if constexpr (AMODE == 1) {
#pragma unroll
            for (int j = 0; j < 4; j++) {
                const float* src = (k0 < 1024) ? (asrc0[j] + k0) : (asrc1[j] + (k0 - 1024));
                gl2lds16(src, &Asf[(j * 256 + (wave << 6)) * 4]);
            }
        } else {
#pragma unroll
            for (int i = 0; i < 2; i++)
                gl2lds16(aptr[i] + k0, &As[(i * 256 + (wave << 6)) * 8]);
        }
#pragma unroll
        for (int i = 0; i < 2; i++)
            gl2lds16(bptr[i] + k0, &Bs[(i * 256 + (wave << 6)) * 8]);

        __syncthreads();   // drains vmcnt before barrier (compiler-inserted)

        bf16x8 af[4], bfr[4];
#pragma unroll
        for (int mt = 0; mt < 4; mt++) {
            if constexpr (AMODE == 1) {
                const int r = wm0 + mt * 16 + l16;
                const int rx = r & 7;
                const f32x4 v0 = *(const f32x4*)&Asf[r * 32 + ((2 * quad) ^ rx) * 4];
                const f32x4 v1 = *(const f32x4*)&Asf[r * 32 + ((2 * quad + 1) ^ rx) * 4];
                bf16x8 t;
#pragma unroll
                for (int e = 0; e < 4; e++) { t[e] = (bf16)v0[e]; t[4 + e] = (bf16)v1[e]; }
                af[mt] = t;
            } else {
                af[mt] = *(const bf16x8*)&As[(wm0 + mt * 16 + l16) * BK + quad * 8];
            }
        }
#pragma unroll
        for (int nt = 0; nt < 4; nt++)
            bfr[nt] = *(const bf16x8*)&Bs[(wn0 + nt * 16 + l16) * BK + quad * 8];
#pragma unroll
        for (int mt = 0; mt < 4; mt++)
#pragma unroll
            for (int nt = 0; nt < 4; nt++)
                acc[mt][nt] = __builtin_amdgcn_mfma_f32_16x16x32_bf16(af[mt], bfr[nt], acc[mt][nt], 0, 0, 0);

        __syncthreads();   // protect LDS from next iteration's staging
    }

    // epilogue: C/D layout col=lane&15, row=quad*4+reg
    float bv[4];
#pragma unroll
    for (int nt = 0; nt < 4; nt++) bv[nt] = bias ? bias[bn0 + wn0 + nt * 16 + l16] : 0.f;
#pragma unroll
    for (int mt = 0; mt < 4; mt++) {
#pragma unroll
        for (int nt = 0; nt < 4; nt++) {
#pragma unroll
            for (int r = 0; r < 4; r++) {
                float v = acc[mt][nt][r] + bv[nt];
                if constexpr (ACT == 1) v = (v > 0.f) ? v : 0.2f * v;
                if constexpr (ACT == 2) v = fminf(fmaxf(v, -1.f), 1.f);
                const int row = bm0 + wm0 + mt * 16 + quad * 4 + r;
                const int col = bn0 + wn0 + nt * 16 + l16;
                if constexpr (OMODE == 0) {
                    ((bf16*)Op)[(size_t)row * N + col] = f2b(v);
                } else {
                    if (col < 512) ((float*)Op)[(size_t)row * 512 + col] = v;
                    else           ((float*)Op2)[(size_t)row * 512 + col - 512] = v;
                }
            }
        }
    }
}

// ---- LDS-tiled transposes: W [K x 512] fp32 -> Wt [512 x K] bf16 ----
struct TP8 { const float* s[8]; bf16* d[8]; };

// eight 512x512 weights in one launch; grid (8,8,8), block 256
__global__ __launch_bounds__(256)
void transpose8_k(TP8 p)
{
    __shared__ float t[64][65];
    const float* __restrict__ src = p.s[blockIdx.z];
    bf16* __restrict__ dst = p.d[blockIdx.z];
    const int tx = threadIdx.x & 63, ty = threadIdx.x >> 6;
    const int k0 = blockIdx.x * 64, n0 = blockIdx.y * 64;
#pragma unroll
    for (int j = 0; j < 16; j++) {
        const int r = j * 4 + ty;
        t[r][tx] = src[(size_t)(k0 + r) * 512 + n0 + tx];
    }
    __syncthreads();
#pragma unroll
    for (int j = 0; j < 16; j++) {
        const int r = j * 4 + ty;
        dst[(size_t)(n0 + r) * 512 + k0 + tx] = f2b(t[tx][r]);
    }
}

// general K x 512 -> 512 x K; grid (K/64, 8), block 256
__global__ __launch_bounds__(256)
void transpose_g_k(const float* __restrict__ src, bf16* __restrict__ dst, int K)
{
    __shared__ float t[64][65];
    const int tx = threadIdx.x & 63, ty = threadIdx.x >> 6;
    const int k0 = blockIdx.x * 64, n0 = blockIdx.y * 64;
#pragma unroll
    for (int j = 0; j < 16; j++) {
        const int r = j * 4 + ty;
        t[r][tx] = src[(size_t)(k0 + r) * 512 + n0 + tx];
    }
    __syncthreads();
#pragma unroll
    for (int j = 0; j < 16; j++) {
        const int r = j * 4 + ty;
        dst[(size_t)(n0 + r) * K + k0 + tx] = f2b(t[tx][r]);
    }
}

// bias concat + gather row indices
__global__ void prep_misc_k(const float* bq, const float* bk, const float* bv,
                            const float* bm, const float* blv,
                            float* bqkv, float* bml,
                            const int* sse, int* rowidx, int Nctx)
{
    const int i = blockIdx.x * 256 + threadIdx.x;
    if (i < 512) {
        bqkv[i] = bq[i]; bqkv[512 + i] = bk[i]; bqkv[1024 + i] = bv[i];
        bml[i] = bm[i];  bml[512 + i] = blv[i];
    }
    if (i < 98304) {
        const int b = i / 48, l = i - b * 48;
        int s = sse[2 * b] + l;
        s = (s < 0) ? 0 : ((s >= Nctx) ? (Nctx - 1) : s);
        rowidx[i] = s;
    }
}

// one block per sequence. seg_out[b] = (sum_{l<len} attn[l,:]) @ V / len
__global__ __launch_bounds__(256, 2)
void attn_k(const bf16* __restrict__ qkv, const int* __restrict__ sse, bf16* __restrict__ seg)
{
    __shared__ bf16 qsh[48 * 128];
    __shared__ bf16 ksh[48 * 128];
    __shared__ float ss[48 * 49];
    __shared__ float wbuf[4 * 48];
    __shared__ float wfin[48];

    const int b = blockIdx.x;
    const int tid = threadIdx.x;
    const int wave = tid >> 6, lane = tid & 63;
    const int len = sse[2 * b + 1] - sse[2 * b];
    const size_t rowbase = (size_t)b * (48 * 1536);

    int pl[9], pm[9]; float sc[9];
    const int np = len * len;
#pragma unroll
    for (int i = 0; i < 9; i++) {
        const int p = tid + i * 256;
        if (p < np) { pl[i] = p / len; pm[i] = p - pl[i] * len; }
        else pl[i] = -1;
        sc[i] = 0.f;
    }

    int srow[3], scol[3];
#pragma unroll
    for (int j = 0; j < 3; j++) { const int t = j * 256 + tid; srow[j] = t >> 4; scol[j] = t & 15; }

    for (int ch = 0; ch < 4; ch++) {
#pragma unroll
        for (int j = 0; j < 3; j++) {
            const int row = srow[j], c = scol[j];
            const bf16* g = qkv + rowbase + (size_t)row * 1536 + (ch << 7) + (c << 3);
            const int lc = row * 128 + ((c ^ (row & 15)) << 3);   // XOR swizzle vs bank conflicts
            *(bf16x8*)&qsh[lc] = *(const bf16x8*)g;
            *(bf16x8*)&ksh[lc] = *(const bf16x8*)(g + 512);
        }
        __syncthreads();
#pragma unroll
        for (int i = 0; i < 9; i++) {
            if (pl[i] < 0) continue;
            const int l = pl[i], m = pm[i];
            const int lbase = l * 128, mbase = m * 128;
            const int lx = l & 15, mx = m & 15;
            float s0 = 0.f, s1 = 0.f;
#pragma unroll 1
            for (int c8 = 0; c8 < 16; c8++) {
                const bf16x8 qv = *(const bf16x8*)&qsh[lbase + ((c8 ^ lx) << 3)];
                const bf16x8 kv = *(const bf16x8*)&ksh[mbase + ((c8 ^ mx) << 3)];
                const u32x4 qu = __builtin_bit_cast(u32x4, qv);
                const u32x4 ku = __builtin_bit_cast(u32x4, kv);
#pragma unroll
                for (int t = 0; t < 4; t++) {
                    s0 += lo16f(qu[t]) * lo16f(ku[t]);
                    s1 += hi16f(qu[t]) * hi16f(ku[t]);
                }
            }
            sc[i] += s0 + s1;
        }
        __syncthreads();
    }

#pragma unroll
    for (int i = 0; i < 9; i++)
        if (pl[i] >= 0) ss[pl[i] * 49 + pm[i]] = sc[i] * 0.044194173824159216f; // 1/sqrt(512)
    __syncthreads();

    float wacc = 0.f;
    for (int l = wave; l < len; l += 4) {
        const float v = (lane < len) ? ss[l * 49 + lane] : -3.0e38f;
        float mx = v;
#pragma unroll
        for (int o = 32; o; o >>= 1) mx = fmaxf(mx, __shfl_xor(mx, o));
        const float e = (lane < len) ? __expf(v - mx) : 0.f;
        float sm = e;
#pragma unroll
        for (int o = 32; o; o >>= 1) sm += __shfl_xor(sm, o);
        wacc += e / sm;
    }
    if (lane < 48) wbuf[wave * 48 + lane] = wacc;
    __syncthreads();
    if (tid < 48) wfin[tid] = wbuf[tid] + wbuf[48 + tid] + wbuf[96 + tid] + wbuf[144 + tid];
    __syncthreads();

    const int d0 = tid * 2;
    float a0 = 0.f, a1 = 0.f;
    for (int m = 0; m < len; m++) {
        const float wv = wfin[m];
        const unsigned u = *(const unsigned*)(qkv + rowbase + (size_t)m * 1536 + 1024 + d0);
        a0 += wv * lo16f(u);
        a1 += wv * hi16f(u);
    }
    const float inv = 1.f / (float)len;
    seg[(size_t)b * 512 + d0]     = f2b(a0 * inv);
    seg[(size_t)b * 512 + d0 + 1] = f2b(a1 * inv);
}

// z = normalize(mean + exp(0.5 lv)*eps) * sqrt(512); also packs decoder inputs U
__global__ __launch_bounds__(256)
void z_k(const float* __restrict__ meanp, const float* __restrict__ lvp,
         const float* __restrict__ eps, const float* __restrict__ tc, const float* __restrict__ tr,
         float* __restrict__ zoutp, bf16* __restrict__ U)
{
    __shared__ float red[4];
    const int b = blockIdx.x, tid = threadIdx.x;
    const int wave = tid >> 6, lane = tid & 63;
    const int d0 = tid * 2;
    float z0[2];
#pragma unroll
    for (int j = 0; j < 2; j++) {
        const float m = meanp[(size_t)b * 512 + d0 + j];
        const float l = lvp[(size_t)b * 512 + d0 + j];
        const float e = eps[(size_t)b * 512 + d0 + j];
        z0[j] = m + __expf(0.5f * l) * e;
    }
    float ssum = z0[0] * z0[0] + z0[1] * z0[1];
#pragma unroll
    for (int o = 32; o; o >>= 1) ssum += __shfl_xor(ssum, o);
    if (lane == 0) red[wave] = ssum;
    __syncthreads();
    const float tot = red[0] + red[1] + red[2] + red[3];
    float nrm = fmaxf(sqrtf(tot), 1e-12f);
    const float s = 22.627416997969522f / nrm;   // sqrt(512)
#pragma unroll
    for (int j = 0; j < 2; j++) {
        const float z = z0[j] * s;
        zoutp[(size_t)b * 512 + d0 + j] = z;
        const bf16 zb = f2b(z);
        U[(size_t)b * 1536 + 1024 + d0 + j] = zb;
        U[(size_t)(2048 + b) * 1536 + 1024 + d0 + j] = zb;
    }
#pragma unroll
    for (int j = 0; j < 4; j++) {
        const int d = tid + j * 256;
        U[(size_t)b * 1536 + d]          = f2b(tc[(size_t)b * 1024 + d]);
        U[(size_t)(2048 + b) * 1536 + d] = f2b(tr[(size_t)b * 1024 + d]);
    }
}

// final decoder dot: out[r] = D2[r,:] . w3 + b3   (one wave per row)
__global__ __launch_bounds__(256)
void dec3_k(const bf16* __restrict__ D2, const float* __restrict__ w3, const float* __restrict__ b3,
            float* __restrict__ out)
{
    const int gw = (blockIdx.x * 256 + threadIdx.x) >> 6;
    const int lane = threadIdx.x & 63;
    const bf16x8 d = *(const bf16x8*)(D2 + (size_t)gw * 512 + lane * 8);
    const u32x4 du = __builtin_bit_cast(u32x4, d);
    float s = 0.f;
#pragma unroll
    for (int t = 0; t < 4; t++) {
        s += lo16f(du[t]) * w3[lane * 8 + 2 * t];
        s += hi16f(du[t]) * w3[lane * 8 + 2 * t + 1];
    }
#pragma unroll
    for (int o = 32; o; o >>= 1) s += __shfl_xor(s, o);
    if (lane == 0) out[gw] = s + b3[0];
}

extern "C" void kernel_launch(void* const* d_in, const int* in_sizes, int n_in,
                              void* d_out, int out_size, void* d_ws, size_t ws_size,
                              hipStream_t stream)
{
    const float* tc    = (const float*)d_in[0];
    const float* tr    = (const float*)d_in[1];
    const float* cc    = (const float*)d_in[2];
    const float* cr    = (const float*)d_in[3];
    const float* eps   = (const float*)d_in[4];
    const float* pe_w1 = (const float*)d_in[5];
    const float* pe_b1 = (const float*)d_in[6];
    const float* pe_w2 = (const float*)d_in[7];
    const float* pe_b2 = (const float*)d_in[8];
    const float* pe_w3 = (const float*)d_in[9];
    const float* pe_b3 = (const float*)d_in[10];
    const float* wq    = (const float*)d_in[11];
    const float* bq    = (const float*)d_in[12];
    const float* wk    = (const float*)d_in[13];
    const float* bk    = (const float*)d_in[14];
    const float* wv    = (const float*)d_in[15];
    const float* bv    = (const float*)d_in[16];
    const float* wm    = (const float*)d_in[17];
    const float* bm    = (const float*)d_in[18];
    const float* wlv   = (const float*)d_in[19];
    const float* blv   = (const float*)d_in[20];
    const float* d_w1  = (const float*)d_in[21];
    const float* d_b1  = (const float*)d_in[22];
    const float* d_w2  = (const float*)d_in[23];
    const float* d_b2  = (const float*)d_in[24];
    const float* d_w3  = (const float*)d_in[25];
    const float* d_b3  = (const float*)d_in[26];
    const int*   sse   = (const int*)d_in[27];
    const int Nctx = in_sizes[2] / 1024;   // 65536

    uint8_t* wsp = (uint8_t*)d_ws;
    size_t off = 0;
    auto alloc = [&](size_t bytes) -> void* {
        void* p = wsp + off;
        off += (bytes + 255) & ~(size_t)255;
        return p;
    };

    bf16* pe_w1t = (bf16*)alloc((size_t)2048 * 512 * 2);
    bf16* pe_w2t = (bf16*)alloc((size_t)512 * 512 * 2);
    bf16* pe_w3t = (bf16*)alloc((size_t)512 * 512 * 2);
    bf16* wqkvt  = (bf16*)alloc((size_t)1536 * 512 * 2);
    bf16* wmlt   = (bf16*)alloc((size_t)1024 * 512 * 2);
    bf16* d_w1t  = (bf16*)alloc((size_t)512 * 1536 * 2);
    bf16* d_w2t  = (bf16*)alloc((size_t)512 * 512 * 2);
    float* bqkv  = (float*)alloc(1536 * 4);
    float* bml   = (float*)alloc(1024 * 4);
    int* rowidx  = (int*)alloc((size_t)98304 * 4);
    bf16* seg    = (bf16*)alloc((size_t)2048 * 512 * 2);
    bf16* U      = (bf16*)alloc((size_t)4096 * 1536 * 2);
    bf16* D1     = (bf16*)alloc((size_t)4096 * 512 * 2);
    bf16* D2     = (bf16*)alloc((size_t)4096 * 512 * 2);
    bf16* hbuf   = (bf16*)alloc((size_t)Nctx * 512 * 2);            // h1, then pair_embed
    bf16* bigbuf = (bf16*)alloc((size_t)98304 * 1536 * 2);          // h2, then qkv
    bf16* h1  = hbuf;
    bf16* h2  = bigbuf;
    bf16* peb = hbuf;
    bf16* qkv = bigbuf;

    float* outp  = (float*)d_out;
    float* meanp = outp + 4096;
    float* lvp   = outp + 4096 + 2048 * 512;
    float* zoutp = outp + 4096 + 2 * 2048 * 512;

    // --- prep: weight transposes (fp32 -> bf16 [N x K]), biases, gather indices
    TP8 tp;
    tp.s[0] = pe_w2; tp.d[0] = pe_w2t;
    tp.s[1] = pe_w3; tp.d[1] = pe_w3t;
    tp.s[2] = wq;    tp.d[2] = wqkvt;
    tp.s[3] = wk;    tp.d[3] = wqkvt + 512 * 512;
    tp.s[4] = wv;    tp.d[4] = wqkvt + 1024 * 512;
    tp.s[5] = wm;    tp.d[5] = wmlt;
    tp.s[6] = wlv;   tp.d[6] = wmlt + 512 * 512;
    tp.s[7] = d_w2;  tp.d[7] = d_w2t;
    transpose8_k<<<dim3(8, 8, 8), 256, 0, stream>>>(tp);
    transpose_g_k<<<dim3(32, 8), 256, 0, stream>>>(pe_w1, pe_w1t, 2048);
    transpose_g_k<<<dim3(24, 8), 256, 0, stream>>>(d_w1, d_w1t, 1536);
    prep_misc_k<<<384, 256, 0, stream>>>(bq, bk, bv, bm, blv, bqkv, bml, sse, rowidx, Nctx);

    // --- pair encoder
    gemm_k<1, 1, 0><<<dim3(4, Nctx / 128), 256, 0, stream>>>(cc, cr, pe_w1t, pe_b1, h1, nullptr, Nctx, 512, 2048, 1024);
    gemm_k<0, 1, 0><<<dim3(4, Nctx / 128), 256, 0, stream>>>(h1, nullptr, pe_w2t, pe_b2, h2, nullptr, Nctx, 512, 512, 512);
    gemm_k<0, 0, 0><<<dim3(4, Nctx / 128), 256, 0, stream>>>(h2, nullptr, pe_w3t, pe_b3, peb, nullptr, Nctx, 512, 512, 512);

    // --- gather + QKV projection (fused)
    gemm_k<2, 0, 0><<<dim3(12, 768), 256, 0, stream>>>(peb, rowidx, wqkvt, bqkv, qkv, nullptr, 98304, 1536, 512, 512);

    // --- attention + masked mean pool
    attn_k<<<2048, 256, 0, stream>>>(qkv, sse, seg);

    // --- latent head: mean / log_var (clipped, fp32 straight to d_out)
    gemm_k<0, 2, 1><<<dim3(8, 16), 256, 0, stream>>>(seg, nullptr, wmlt, bml, meanp, lvp, 2048, 1024, 512, 512);

    // --- z + decoder input packing
    z_k<<<2048, 256, 0, stream>>>(meanp, lvp, eps, tc, tr, zoutp, U);

    // --- decoder (both targets stacked: rows 0..2047 chosen, 2048..4095 rejected)
    gemm_k<0, 1, 0><<<dim3(4, 32), 256, 0, stream>>>(U, nullptr, d_w1t, d_b1, D1, nullptr, 4096, 512, 1536, 1536);
    gemm_k<0, 1, 0><<<dim3(4, 32), 256, 0, stream>>>(D1, nullptr, d_w2t, d_b2, D2, nullptr, 4096, 512, 512, 512);
    dec3_k<<<1024, 256, 0, stream>>>(D2, d_w3, d_b3, outp);

    (void)n_in; (void)out_size; (void)ws_size; (void)in_sizes;
}

// Round 2
// 1337.986 us; speedup vs baseline: 1.0379x; 1.0379x over previous
//
#include <hip/hip_runtime.h>
#include <stdint.h>

typedef __bf16 bf16;
typedef __attribute__((ext_vector_type(8))) __bf16 bf16x8;
typedef __attribute__((ext_vector_type(4))) float f32x4;
typedef __attribute__((ext_vector_type(4))) unsigned int u32x4;

typedef __attribute__((address_space(1))) unsigned gas_u32;
typedef __attribute__((address_space(3))) unsigned las_u32;

__device__ __forceinline__ unsigned short f2b_bits(float f) {
    unsigned u = __builtin_bit_cast(unsigned, f);
    u += 0x7fffu + ((u >> 16) & 1u);   // RNE
    return (unsigned short)(u >> 16);
}
__device__ __forceinline__ bf16 f2b(float f) { return __builtin_bit_cast(bf16, f2b_bits(f)); }
__device__ __forceinline__ float lo16f(unsigned u) { return __builtin_bit_cast(float, u << 16); }
__device__ __forceinline__ float hi16f(unsigned u) { return __builtin_bit_cast(float, u & 0xffff0000u); }

// async global->LDS, 16B per lane; LDS dest is wave-uniform base (+lane*16 by HW)
__device__ __forceinline__ void gl2lds16(const void* g, void* l) {
    __builtin_amdgcn_global_load_lds((gas_u32*)(uintptr_t)g, (las_u32*)(uintptr_t)l, 16, 0, 0);
}

#define BM 128
#define BN 128
#define BK 32

// AMODE: 0 = A bf16 [M x lda]; 1 = A = concat(cc,cr) fp32 (K=2048, per-half lda=1024),
//            reg-staged fp32 load + cvt->bf16 + ds_write (LDS tile identical to AMODE 0);
//        2 = A bf16 gathered: row r -> Ap row rowidx[r] (Ap2 = int*)
// ACT:   0 none, 1 leaky-relu(0.2), 2 clip(-1,1)
// OMODE: 0 = bf16 out [M x N]; 1 = fp32 split (N=1024): col<512 -> Op, col>=512 -> Op2, ldc=512
template<int AMODE, int ACT, int OMODE>
__global__ __launch_bounds__(256, 2)
void gemm_k(const void* __restrict__ Ap, const void* __restrict__ Ap2,
            const bf16* __restrict__ Bt, const float* __restrict__ bias,
            void* __restrict__ Op, void* __restrict__ Op2,
            int M, int N, int K, int lda)
{
    __shared__ __align__(16) bf16 As[BM * BK];
    __shared__ __align__(16) bf16 Bs[BN * BK];

    const int tid  = threadIdx.x;
    const int wave = tid >> 6;
    const int lane = tid & 63;
    const int quad = lane >> 4;
    const int l16  = lane & 15;
    const int bm0 = blockIdx.y * BM;
    const int bn0 = blockIdx.x * BN;
    const int wm0 = (wave >> 1) << 6;
    const int wn0 = (wave & 1) << 6;

    f32x4 acc[4][4];
#pragma unroll
    for (int a = 0; a < 4; a++)
#pragma unroll
        for (int c = 0; c < 4; c++) acc[a][c] = {0.f, 0.f, 0.f, 0.f};

    // hoisted staging pointers
    const bf16* aptr[2];
    const float* a0base = nullptr;   // cc half (AMODE 1)
    const float* a1base = nullptr;   // cr half
    f32x4 areg[4];
    if constexpr (AMODE == 1) {
        // thread t: row = t>>1, k-halfgroup = t&1 (16 fp32 = 4 x f32x4)
        a0base = (const float*)Ap  + (size_t)(bm0 + (tid >> 1)) * 1024 + (tid & 1) * 16;
        a1base = (const float*)Ap2 + (size_t)(bm0 + (tid >> 1)) * 1024 + (tid & 1) * 16;
#pragma unroll
        for (int j = 0; j < 4; j++) areg[j] = *(const f32x4*)(a0base + j * 4);   // k0 = 0
    } else {
#pragma unroll
        for (int i = 0; i < 2; i++) {
            const int s = i * 256 + tid;
            const int arow = s >> 2, kp = s & 3;
            size_t rbase;
            if constexpr (AMODE == 2) rbase = (size_t)((const int*)Ap2)[bm0 + arow] * (size_t)lda;
            else                      rbase = (size_t)(bm0 + arow) * (size_t)lda;
            aptr[i] = (const bf16*)Ap + rbase + kp * 8;
        }
    }
    const bf16* bptr[2];
#pragma unroll
    for (int i = 0; i < 2; i++) {
        const int s = i * 256 + tid;
        const int brow = s >> 2, kp = s & 3;
        bptr[i] = Bt + (size_t)(bn0 + brow) * (size_t)K + kp * 8;
    }

    for (int k0 = 0; k0 < K; k0 += BK) {
#pragma unroll
        for (int i = 0; i < 2; i++)
            gl2lds16(bptr[i] + k0, &Bs[(i * 256 + (wave << 6)) * 8]);

        if constexpr (AMODE == 1) {
            // convert the regs loaded last iteration, write bf16 tile, then prefetch next
            bf16x8 w0, w1;
#pragma unroll
            for (int e = 0; e < 4; e++) {
                w0[e]     = (bf16)areg[0][e];
                w0[4 + e] = (bf16)areg[1][e];
                w1[e]     = (bf16)areg[2][e];
                w1[4 + e] = (bf16)areg[3][e];
            }
            bf16* dst = &As[(tid >> 1) * BK + (tid & 1) * 16];
            *(bf16x8*)dst       = w0;
            *(bf16x8*)(dst + 8) = w1;
            const int kn = (k0 + BK < K) ? (k0 + BK) : 0;   // clamp: dead reload of tile 0 on last iter
            const float* s = (kn < 1024) ? (a0base + kn) : (a1base + (kn - 1024));
#pragma unroll
            for (int j = 0; j < 4; j++) areg[j] = *(const f32x4*)(s + j * 4);
        } else {
#pragma unroll
            for (int i = 0; i < 2; i++)
                gl2lds16(aptr[i] + k0, &As[(i * 256 + (wave << 6)) * 8]);
        }

        __syncthreads();   // drains vmcnt + lgkmcnt before barrier (compiler-inserted)

        bf16x8 af[4], bfr[4];
#pragma unroll
        for (int mt = 0; mt < 4; mt++)
            af[mt] = *(const bf16x8*)&As[(wm0 + mt * 16 + l16) * BK + quad * 8];
#pragma unroll
        for (int nt = 0; nt < 4; nt++)
            bfr[nt] = *(const bf16x8*)&Bs[(wn0 + nt * 16 + l16) * BK + quad * 8];
#pragma unroll
        for (int mt = 0; mt < 4; mt++)
#pragma unroll
            for (int nt = 0; nt < 4; nt++)
                acc[mt][nt] = __builtin_amdgcn_mfma_f32_16x16x32_bf16(af[mt], bfr[nt], acc[mt][nt], 0, 0, 0);

        __syncthreads();   // protect LDS from next iteration's staging
    }

    // epilogue: C/D layout col=lane&15, row=quad*4+reg
    float bv[4];
#pragma unroll
    for (int nt = 0; nt < 4; nt++) bv[nt] = bias ? bias[bn0 + wn0 + nt * 16 + l16] : 0.f;
#pragma unroll
    for (int mt = 0; mt < 4; mt++) {
#pragma unroll
        for (int nt = 0; nt < 4; nt++) {
#pragma unroll
            for (int r = 0; r < 4; r++) {
                float v = acc[mt][nt][r] + bv[nt];
                if constexpr (ACT == 1) v = (v > 0.f) ? v : 0.2f * v;
                if constexpr (ACT == 2) v = fminf(fmaxf(v, -1.f), 1.f);
                const int row = bm0 + wm0 + mt * 16 + quad * 4 + r;
                const int col = bn0 + wn0 + nt * 16 + l16;
                if constexpr (OMODE == 0) {
                    ((bf16*)Op)[(size_t)row * N + col] = f2b(v);
                } else {
                    if (col < 512) ((float*)Op)[(size_t)row * 512 + col] = v;
                    else           ((float*)Op2)[(size_t)row * 512 + col - 512] = v;
                }
            }
        }
    }
}

// ---- LDS-tiled transposes: W [K x 512] fp32 -> Wt [512 x K] bf16 ----
struct TP8 { const float* s[8]; bf16* d[8]; };

// eight 512x512 weights in one launch; grid (8,8,8), block 256
__global__ __launch_bounds__(256)
void transpose8_k(TP8 p)
{
    __shared__ float t[64][65];
    const float* __restrict__ src = p.s[blockIdx.z];
    bf16* __restrict__ dst = p.d[blockIdx.z];
    const int tx = threadIdx.x & 63, ty = threadIdx.x >> 6;
    const int k0 = blockIdx.x * 64, n0 = blockIdx.y * 64;
#pragma unroll
    for (int j = 0; j < 16; j++) {
        const int r = j * 4 + ty;
        t[r][tx] = src[(size_t)(k0 + r) * 512 + n0 + tx];
    }
    __syncthreads();
#pragma unroll
    for (int j = 0; j < 16; j++) {
        const int r = j * 4 + ty;
        dst[(size_t)(n0 + r) * 512 + k0 + tx] = f2b(t[tx][r]);
    }
}

// general K x 512 -> 512 x K; grid (K/64, 8), block 256
__global__ __launch_bounds__(256)
void transpose_g_k(const float* __restrict__ src, bf16* __restrict__ dst, int K)
{
    __shared__ float t[64][65];
    const int tx = threadIdx.x & 63, ty = threadIdx.x >> 6;
    const int k0 = blockIdx.x * 64, n0 = blockIdx.y * 64;
#pragma unroll
    for (int j = 0; j < 16; j++) {
        const int r = j * 4 + ty;
        t[r][tx] = src[(size_t)(k0 + r) * 512 + n0 + tx];
    }
    __syncthreads();
#pragma unroll
    for (int j = 0; j < 16; j++) {
        const int r = j * 4 + ty;
        dst[(size_t)(n0 + r) * K + k0 + tx] = f2b(t[tx][r]);
    }
}

// bias concat (rowidx gather removed: QKV now computed on unpadded rows)
__global__ void prep_misc_k(const float* bq, const float* bk, const float* bv,
                            const float* bm, const float* blv,
                            float* bqkv, float* bml)
{
    const int i = blockIdx.x * 256 + threadIdx.x;
    if (i < 512) {
        bqkv[i] = bq[i]; bqkv[512 + i] = bk[i]; bqkv[1024 + i] = bv[i];
        bml[i] = bm[i];  bml[512 + i] = blv[i];
    }
}

// one block per sequence. seg_out[b] = (sum_{l<len} attn[l,:]) @ V / len
// qkv is UNPADDED [Nctx x 1536]; sequence rows are consecutive starting at sse[2b].
// Rows l >= len read the next sequence's data but are fully masked out of the math.
__global__ __launch_bounds__(256, 2)
void attn_k(const bf16* __restrict__ qkv, const int* __restrict__ sse, bf16* __restrict__ seg)
{
    __shared__ bf16 qsh[48 * 128];
    __shared__ bf16 ksh[48 * 128];
    __shared__ float ss[48 * 49];
    __shared__ float wbuf[4 * 48];
    __shared__ float wfin[48];

    const int b = blockIdx.x;
    const int tid = threadIdx.x;
    const int wave = tid >> 6, lane = tid & 63;
    const int st  = sse[2 * b];
    const int len = sse[2 * b + 1] - st;
    const size_t rowbase = (size_t)st * 1536;

    int pl[9], pm[9]; float sc[9];
    const int np = len * len;
#pragma unroll
    for (int i = 0; i < 9; i++) {
        const int p = tid + i * 256;
        if (p < np) { pl[i] = p / len; pm[i] = p - pl[i] * len; }
        else pl[i] = -1;
        sc[i] = 0.f;
    }

    int srow[3], scol[3];
#pragma unroll
    for (int j = 0; j < 3; j++) { const int t = j * 256 + tid; srow[j] = t >> 4; scol[j] = t & 15; }

    for (int ch = 0; ch < 4; ch++) {
#pragma unroll
        for (int j = 0; j < 3; j++) {
            const int row = srow[j], c = scol[j];
            const bf16* g = qkv + rowbase + (size_t)row * 1536 + (ch << 7) + (c << 3);
            const int lc = row * 128 + ((c ^ (row & 15)) << 3);   // XOR swizzle vs bank conflicts
            *(bf16x8*)&qsh[lc] = *(const bf16x8*)g;
            *(bf16x8*)&ksh[lc] = *(const bf16x8*)(g + 512);
        }
        __syncthreads();
#pragma unroll
        for (int i = 0; i < 9; i++) {
            if (pl[i] < 0) continue;
            const int l = pl[i], m = pm[i];
            const int lbase = l * 128, mbase = m * 128;
            const int lx = l & 15, mx = m & 15;
            float s0 = 0.f, s1 = 0.f;
#pragma unroll 1
            for (int c8 = 0; c8 < 16; c8++) {
                const bf16x8 qv = *(const bf16x8*)&qsh[lbase + ((c8 ^ lx) << 3)];
                const bf16x8 kv = *(const bf16x8*)&ksh[mbase + ((c8 ^ mx) << 3)];
                const u32x4 qu = __builtin_bit_cast(u32x4, qv);
                const u32x4 ku = __builtin_bit_cast(u32x4, kv);
#pragma unroll
                for (int t = 0; t < 4; t++) {
                    s0 += lo16f(qu[t]) * lo16f(ku[t]);
                    s1 += hi16f(qu[t]) * hi16f(ku[t]);
                }
            }
            sc[i] += s0 + s1;
        }
        __syncthreads();
    }

#pragma unroll
    for (int i = 0; i < 9; i++)
        if (pl[i] >= 0) ss[pl[i] * 49 + pm[i]] = sc[i] * 0.044194173824159216f; // 1/sqrt(512)
    __syncthreads();

    float wacc = 0.f;
    for (int l = wave; l < len; l += 4) {
        const float v = (lane < len) ? ss[l * 49 + lane] : -3.0e38f;
        float mx = v;
#pragma unroll
        for (int o = 32; o; o >>= 1) mx = fmaxf(mx, __shfl_xor(mx, o));
        const float e = (lane < len) ? __expf(v - mx) : 0.f;
        float sm = e;
#pragma unroll
        for (int o = 32; o; o >>= 1) sm += __shfl_xor(sm, o);
        wacc += e / sm;
    }
    if (lane < 48) wbuf[wave * 48 + lane] = wacc;
    __syncthreads();
    if (tid < 48) wfin[tid] = wbuf[tid] + wbuf[48 + tid] + wbuf[96 + tid] + wbuf[144 + tid];
    __syncthreads();

    const int d0 = tid * 2;
    float a0 = 0.f, a1 = 0.f;
    for (int m = 0; m < len; m++) {
        const float wv = wfin[m];
        const unsigned u = *(const unsigned*)(qkv + rowbase + (size_t)m * 1536 + 1024 + d0);
        a0 += wv * lo16f(u);
        a1 += wv * hi16f(u);
    }
    const float inv = 1.f / (float)len;
    seg[(size_t)b * 512 + d0]     = f2b(a0 * inv);
    seg[(size_t)b * 512 + d0 + 1] = f2b(a1 * inv);
}

// z = normalize(mean + exp(0.5 lv)*eps) * sqrt(512); also packs decoder inputs U
__global__ __launch_bounds__(256)
void z_k(const float* __restrict__ meanp, const float* __restrict__ lvp,
         const float* __restrict__ eps, const float* __restrict__ tc, const float* __restrict__ tr,
         float* __restrict__ zoutp, bf16* __restrict__ U)
{
    __shared__ float red[4];
    const int b = blockIdx.x, tid = threadIdx.x;
    const int wave = tid >> 6, lane = tid & 63;
    const int d0 = tid * 2;
    float z0[2];
#pragma unroll
    for (int j = 0; j < 2; j++) {
        const float m = meanp[(size_t)b * 512 + d0 + j];
        const float l = lvp[(size_t)b * 512 + d0 + j];
        const float e = eps[(size_t)b * 512 + d0 + j];
        z0[j] = m + __expf(0.5f * l) * e;
    }
    float ssum = z0[0] * z0[0] + z0[1] * z0[1];
#pragma unroll
    for (int o = 32; o; o >>= 1) ssum += __shfl_xor(ssum, o);
    if (lane == 0) red[wave] = ssum;
    __syncthreads();
    const float tot = red[0] + red[1] + red[2] + red[3];
    float nrm = fmaxf(sqrtf(tot), 1e-12f);
    const float s = 22.627416997969522f / nrm;   // sqrt(512)
#pragma unroll
    for (int j = 0; j < 2; j++) {
        const float z = z0[j] * s;
        zoutp[(size_t)b * 512 + d0 + j] = z;
        const bf16 zb = f2b(z);
        U[(size_t)b * 1536 + 1024 + d0 + j] = zb;
        U[(size_t)(2048 + b) * 1536 + 1024 + d0 + j] = zb;
    }
#pragma unroll
    for (int j = 0; j < 4; j++) {
        const int d = tid + j * 256;
        U[(size_t)b * 1536 + d]          = f2b(tc[(size_t)b * 1024 + d]);
        U[(size_t)(2048 + b) * 1536 + d] = f2b(tr[(size_t)b * 1024 + d]);
    }
}

// final decoder dot: out[r] = D2[r,:] . w3 + b3   (one wave per row)
__global__ __launch_bounds__(256)
void dec3_k(const bf16* __restrict__ D2, const float* __restrict__ w3, const float* __restrict__ b3,
            float* __restrict__ out)
{
    const int gw = (blockIdx.x * 256 + threadIdx.x) >> 6;
    const int lane = threadIdx.x & 63;
    const bf16x8 d = *(const bf16x8*)(D2 + (size_t)gw * 512 + lane * 8);
    const u32x4 du = __builtin_bit_cast(u32x4, d);
    float s = 0.f;
#pragma unroll
    for (int t = 0; t < 4; t++) {
        s += lo16f(du[t]) * w3[lane * 8 + 2 * t];
        s += hi16f(du[t]) * w3[lane * 8 + 2 * t + 1];
    }
#pragma unroll
    for (int o = 32; o; o >>= 1) s += __shfl_xor(s, o);
    if (lane == 0) out[gw] = s + b3[0];
}

extern "C" void kernel_launch(void* const* d_in, const int* in_sizes, int n_in,
                              void* d_out, int out_size, void* d_ws, size_t ws_size,
                              hipStream_t stream)
{
    const float* tc    = (const float*)d_in[0];
    const float* tr    = (const float*)d_in[1];
    const float* cc    = (const float*)d_in[2];
    const float* cr    = (const float*)d_in[3];
    const float* eps   = (const float*)d_in[4];
    const float* pe_w1 = (const float*)d_in[5];
    const float* pe_b1 = (const float*)d_in[6];
    const float* pe_w2 = (const float*)d_in[7];
    const float* pe_b2 = (const float*)d_in[8];
    const float* pe_w3 = (const float*)d_in[9];
    const float* pe_b3 = (const float*)d_in[10];
    const float* wq    = (const float*)d_in[11];
    const float* bq    = (const float*)d_in[12];
    const float* wk    = (const float*)d_in[13];
    const float* bk    = (const float*)d_in[14];
    const float* wv    = (const float*)d_in[15];
    const float* bv    = (const float*)d_in[16];
    const float* wm    = (const float*)d_in[17];
    const float* bm    = (const float*)d_in[18];
    const float* wlv   = (const float*)d_in[19];
    const float* blv   = (const float*)d_in[20];
    const float* d_w1  = (const float*)d_in[21];
    const float* d_b1  = (const float*)d_in[22];
    const float* d_w2  = (const float*)d_in[23];
    const float* d_b2  = (const float*)d_in[24];
    const float* d_w3  = (const float*)d_in[25];
    const float* d_b3  = (const float*)d_in[26];
    const int*   sse   = (const int*)d_in[27];
    const int Nctx = in_sizes[2] / 1024;   // 65536

    uint8_t* wsp = (uint8_t*)d_ws;
    size_t off = 0;
    auto alloc = [&](size_t bytes) -> void* {
        void* p = wsp + off;
        off += (bytes + 255) & ~(size_t)255;
        return p;
    };

    bf16* pe_w1t = (bf16*)alloc((size_t)2048 * 512 * 2);
    bf16* pe_w2t = (bf16*)alloc((size_t)512 * 512 * 2);
    bf16* pe_w3t = (bf16*)alloc((size_t)512 * 512 * 2);
    bf16* wqkvt  = (bf16*)alloc((size_t)1536 * 512 * 2);
    bf16* wmlt   = (bf16*)alloc((size_t)1024 * 512 * 2);
    bf16* d_w1t  = (bf16*)alloc((size_t)512 * 1536 * 2);
    bf16* d_w2t  = (bf16*)alloc((size_t)512 * 512 * 2);
    float* bqkv  = (float*)alloc(1536 * 4);
    float* bml   = (float*)alloc(1024 * 4);
    bf16* seg    = (bf16*)alloc((size_t)2048 * 512 * 2);
    bf16* U      = (bf16*)alloc((size_t)4096 * 1536 * 2);
    bf16* D1     = (bf16*)alloc((size_t)4096 * 512 * 2);
    bf16* D2     = (bf16*)alloc((size_t)4096 * 512 * 2);
    bf16* hbuf   = (bf16*)alloc((size_t)Nctx * 512 * 2);            // h1, then pair_embed
    bf16* bigbuf = (bf16*)alloc((size_t)Nctx * 1536 * 2);           // h2, then qkv (unpadded)
    bf16* h1  = hbuf;
    bf16* h2  = bigbuf;
    bf16* peb = hbuf;
    bf16* qkv = bigbuf;

    float* outp  = (float*)d_out;
    float* meanp = outp + 4096;
    float* lvp   = outp + 4096 + 2048 * 512;
    float* zoutp = outp + 4096 + 2 * 2048 * 512;

    // --- prep: weight transposes (fp32 -> bf16 [N x K]), biases
    TP8 tp;
    tp.s[0] = pe_w2; tp.d[0] = pe_w2t;
    tp.s[1] = pe_w3; tp.d[1] = pe_w3t;
    tp.s[2] = wq;    tp.d[2] = wqkvt;
    tp.s[3] = wk;    tp.d[3] = wqkvt + 512 * 512;
    tp.s[4] = wv;    tp.d[4] = wqkvt + 1024 * 512;
    tp.s[5] = wm;    tp.d[5] = wmlt;
    tp.s[6] = wlv;   tp.d[6] = wmlt + 512 * 512;
    tp.s[7] = d_w2;  tp.d[7] = d_w2t;
    transpose8_k<<<dim3(8, 8, 8), 256, 0, stream>>>(tp);
    transpose_g_k<<<dim3(32, 8), 256, 0, stream>>>(pe_w1, pe_w1t, 2048);
    transpose_g_k<<<dim3(24, 8), 256, 0, stream>>>(d_w1, d_w1t, 1536);
    prep_misc_k<<<2, 256, 0, stream>>>(bq, bk, bv, bm, blv, bqkv, bml);

    // --- pair encoder
    gemm_k<1, 1, 0><<<dim3(4, Nctx / 128), 256, 0, stream>>>(cc, cr, pe_w1t, pe_b1, h1, nullptr, Nctx, 512, 2048, 1024);
    gemm_k<0, 1, 0><<<dim3(4, Nctx / 128), 256, 0, stream>>>(h1, nullptr, pe_w2t, pe_b2, h2, nullptr, Nctx, 512, 512, 512);
    gemm_k<0, 0, 0><<<dim3(4, Nctx / 128), 256, 0, stream>>>(h2, nullptr, pe_w3t, pe_b3, peb, nullptr, Nctx, 512, 512, 512);

    // --- QKV projection on UNPADDED rows (sequences are consecutive rows of peb)
    gemm_k<0, 0, 0><<<dim3(12, Nctx / 128), 256, 0, stream>>>(peb, nullptr, wqkvt, bqkv, qkv, nullptr, Nctx, 1536, 512, 512);

    // --- attention + masked mean pool (indexes qkv by sse[2b] directly)
    attn_k<<<2048, 256, 0, stream>>>(qkv, sse, seg);

    // --- latent head: mean / log_var (clipped, fp32 straight to d_out)
    gemm_k<0, 2, 1><<<dim3(8, 16), 256, 0, stream>>>(seg, nullptr, wmlt, bml, meanp, lvp, 2048, 1024, 512, 512);

    // --- z + decoder input packing
    z_k<<<2048, 256, 0, stream>>>(meanp, lvp, eps, tc, tr, zoutp, U);

    // --- decoder (both targets stacked: rows 0..2047 chosen, 2048..4095 rejected)
    gemm_k<0, 1, 0><<<dim3(4, 32), 256, 0, stream>>>(U, nullptr, d_w1t, d_b1, D1, nullptr, 4096, 512, 1536, 1536);
    gemm_k<0, 1, 0><<<dim3(4, 32), 256, 0, stream>>>(D1, nullptr, d_w2t, d_b2, D2, nullptr, 4096, 512, 512, 512);
    dec3_k<<<1024, 256, 0, stream>>>(D2, d_w3, d_b3, outp);

    (void)n_in; (void)out_size; (void)ws_size; (void)in_sizes;
}

// Round 3
// 1272.098 us; speedup vs baseline: 1.0916x; 1.0518x over previous
//
#include <hip/hip_runtime.h>
#include <stdint.h>

typedef __bf16 bf16;
typedef __attribute__((ext_vector_type(8))) __bf16 bf16x8;
typedef __attribute__((ext_vector_type(4))) float f32x4;
typedef __attribute__((ext_vector_type(4))) unsigned int u32x4;

typedef __attribute__((address_space(1))) unsigned gas_u32;
typedef __attribute__((address_space(3))) unsigned las_u32;

__device__ __forceinline__ unsigned short f2b_bits(float f) {
    unsigned u = __builtin_bit_cast(unsigned, f);
    u += 0x7fffu + ((u >> 16) & 1u);   // RNE
    return (unsigned short)(u >> 16);
}
__device__ __forceinline__ bf16 f2b(float f) { return __builtin_bit_cast(bf16, f2b_bits(f)); }
__device__ __forceinline__ float lo16f(unsigned u) { return __builtin_bit_cast(float, u << 16); }
__device__ __forceinline__ float hi16f(unsigned u) { return __builtin_bit_cast(float, u & 0xffff0000u); }

// async global->LDS, 16B per lane; LDS dest is wave-uniform base (+lane*16 by HW)
__device__ __forceinline__ void gl2lds16(const void* g, void* l) {
    __builtin_amdgcn_global_load_lds((gas_u32*)(uintptr_t)g, (las_u32*)(uintptr_t)l, 16, 0, 0);
}

#define BM 128
#define BN 128
#define BK 32

// AMODE: 0 = A bf16 [M x lda]; 1 = A = concat(cc,cr) fp32 (K=2048, per-half lda=1024),
//            reg-staged fp32 load + cvt->bf16 + ds_write (LDS tile identical to AMODE 0);
//        2 = A bf16 gathered: row r -> Ap row rowidx[r] (Ap2 = int*)
// ACT:   0 none, 1 leaky-relu(0.2), 2 clip(-1,1)
// OMODE: 0 = bf16 out [M x N]; 1 = fp32 split (N=1024): col<512 -> Op, col>=512 -> Op2, ldc=512
template<int AMODE, int ACT, int OMODE>
__global__ __launch_bounds__(256, 2)
void gemm_k(const void* __restrict__ Ap, const void* __restrict__ Ap2,
            const bf16* __restrict__ Bt, const float* __restrict__ bias,
            void* __restrict__ Op, void* __restrict__ Op2,
            int M, int N, int K, int lda)
{
    __shared__ __align__(16) bf16 As[BM * BK];
    __shared__ __align__(16) bf16 Bs[BN * BK];

    const int tid  = threadIdx.x;
    const int wave = tid >> 6;
    const int lane = tid & 63;
    const int quad = lane >> 4;
    const int l16  = lane & 15;

    // XCD-aware chunked swizzle (T1): dispatch id d -> work id (d&7)*(nwg/8) + d>>3.
    // Consecutive N-tiles of one A-band then run temporally adjacent on ONE XCD ->
    // the A-band is fetched from HBM once and re-read from that XCD's L2.
    const int nwg = gridDim.x * gridDim.y;
    int bid = blockIdx.y * gridDim.x + blockIdx.x;
    if ((nwg & 7) == 0) bid = (bid & 7) * (nwg >> 3) + (bid >> 3);
    const int bx = bid % gridDim.x;
    const int by = bid / gridDim.x;
    const int bm0 = by * BM;
    const int bn0 = bx * BN;

    const int wm0 = (wave >> 1) << 6;
    const int wn0 = (wave & 1) << 6;

    f32x4 acc[4][4];
#pragma unroll
    for (int a = 0; a < 4; a++)
#pragma unroll
        for (int c = 0; c < 4; c++) acc[a][c] = {0.f, 0.f, 0.f, 0.f};

    // hoisted staging pointers
    const bf16* aptr[2];
    const float* a0base = nullptr;   // cc half (AMODE 1)
    const float* a1base = nullptr;   // cr half
    f32x4 areg[4];
    if constexpr (AMODE == 1) {
        // thread t: row = t>>1, k-halfgroup = t&1 (16 fp32 = 4 x f32x4)
        a0base = (const float*)Ap  + (size_t)(bm0 + (tid >> 1)) * 1024 + (tid & 1) * 16;
        a1base = (const float*)Ap2 + (size_t)(bm0 + (tid >> 1)) * 1024 + (tid & 1) * 16;
#pragma unroll
        for (int j = 0; j < 4; j++) areg[j] = *(const f32x4*)(a0base + j * 4);   // k0 = 0
    } else {
#pragma unroll
        for (int i = 0; i < 2; i++) {
            const int s = i * 256 + tid;
            const int arow = s >> 2, kp = s & 3;
            size_t rbase;
            if constexpr (AMODE == 2) rbase = (size_t)((const int*)Ap2)[bm0 + arow] * (size_t)lda;
            else                      rbase = (size_t)(bm0 + arow) * (size_t)lda;
            aptr[i] = (const bf16*)Ap + rbase + kp * 8;
        }
    }
    const bf16* bptr[2];
#pragma unroll
    for (int i = 0; i < 2; i++) {
        const int s = i * 256 + tid;
        const int brow = s >> 2, kp = s & 3;
        bptr[i] = Bt + (size_t)(bn0 + brow) * (size_t)K + kp * 8;
    }

    for (int k0 = 0; k0 < K; k0 += BK) {
#pragma unroll
        for (int i = 0; i < 2; i++)
            gl2lds16(bptr[i] + k0, &Bs[(i * 256 + (wave << 6)) * 8]);

        if constexpr (AMODE == 1) {
            // convert the regs loaded last iteration, write bf16 tile, then prefetch next
            bf16x8 w0, w1;
#pragma unroll
            for (int e = 0; e < 4; e++) {
                w0[e]     = (bf16)areg[0][e];
                w0[4 + e] = (bf16)areg[1][e];
                w1[e]     = (bf16)areg[2][e];
                w1[4 + e] = (bf16)areg[3][e];
            }
            bf16* dst = &As[(tid >> 1) * BK + (tid & 1) * 16];
            *(bf16x8*)dst       = w0;
            *(bf16x8*)(dst + 8) = w1;
            const int kn = (k0 + BK < K) ? (k0 + BK) : 0;   // clamp: dead reload of tile 0 on last iter
            const float* s = (kn < 1024) ? (a0base + kn) : (a1base + (kn - 1024));
#pragma unroll
            for (int j = 0; j < 4; j++) areg[j] = *(const f32x4*)(s + j * 4);
        } else {
#pragma unroll
            for (int i = 0; i < 2; i++)
                gl2lds16(aptr[i] + k0, &As[(i * 256 + (wave << 6)) * 8]);
        }

        __syncthreads();   // drains vmcnt + lgkmcnt before barrier (compiler-inserted)

        bf16x8 af[4], bfr[4];
#pragma unroll
        for (int mt = 0; mt < 4; mt++)
            af[mt] = *(const bf16x8*)&As[(wm0 + mt * 16 + l16) * BK + quad * 8];
#pragma unroll
        for (int nt = 0; nt < 4; nt++)
            bfr[nt] = *(const bf16x8*)&Bs[(wn0 + nt * 16 + l16) * BK + quad * 8];
#pragma unroll
        for (int mt = 0; mt < 4; mt++)
#pragma unroll
            for (int nt = 0; nt < 4; nt++)
                acc[mt][nt] = __builtin_amdgcn_mfma_f32_16x16x32_bf16(af[mt], bfr[nt], acc[mt][nt], 0, 0, 0);

        __syncthreads();   // protect LDS from next iteration's staging
    }

    // epilogue: C/D layout col=lane&15, row=quad*4+reg
    float bv[4];
#pragma unroll
    for (int nt = 0; nt < 4; nt++) bv[nt] = bias ? bias[bn0 + wn0 + nt * 16 + l16] : 0.f;
#pragma unroll
    for (int mt = 0; mt < 4; mt++) {
#pragma unroll
        for (int nt = 0; nt < 4; nt++) {
#pragma unroll
            for (int r = 0; r < 4; r++) {
                float v = acc[mt][nt][r] + bv[nt];
                if constexpr (ACT == 1) v = (v > 0.f) ? v : 0.2f * v;
                if constexpr (ACT == 2) v = fminf(fmaxf(v, -1.f), 1.f);
                const int row = bm0 + wm0 + mt * 16 + quad * 4 + r;
                const int col = bn0 + wn0 + nt * 16 + l16;
                if constexpr (OMODE == 0) {
                    ((bf16*)Op)[(size_t)row * N + col] = f2b(v);
                } else {
                    if (col < 512) ((float*)Op)[(size_t)row * 512 + col] = v;
                    else           ((float*)Op2)[(size_t)row * 512 + col - 512] = v;
                }
            }
        }
    }
}

// ---- LDS-tiled transposes: W [K x 512] fp32 -> Wt [512 x K] bf16 ----
struct TP8 { const float* s[8]; bf16* d[8]; };

// eight 512x512 weights in one launch; grid (8,8,8), block 256
__global__ __launch_bounds__(256)
void transpose8_k(TP8 p)
{
    __shared__ float t[64][65];
    const float* __restrict__ src = p.s[blockIdx.z];
    bf16* __restrict__ dst = p.d[blockIdx.z];
    const int tx = threadIdx.x & 63, ty = threadIdx.x >> 6;
    const int k0 = blockIdx.x * 64, n0 = blockIdx.y * 64;
#pragma unroll
    for (int j = 0; j < 16; j++) {
        const int r = j * 4 + ty;
        t[r][tx] = src[(size_t)(k0 + r) * 512 + n0 + tx];
    }
    __syncthreads();
#pragma unroll
    for (int j = 0; j < 16; j++) {
        const int r = j * 4 + ty;
        dst[(size_t)(n0 + r) * 512 + k0 + tx] = f2b(t[tx][r]);
    }
}

// general K x 512 -> 512 x K; grid (K/64, 8), block 256
__global__ __launch_bounds__(256)
void transpose_g_k(const float* __restrict__ src, bf16* __restrict__ dst, int K)
{
    __shared__ float t[64][65];
    const int tx = threadIdx.x & 63, ty = threadIdx.x >> 6;
    const int k0 = blockIdx.x * 64, n0 = blockIdx.y * 64;
#pragma unroll
    for (int j = 0; j < 16; j++) {
        const int r = j * 4 + ty;
        t[r][tx] = src[(size_t)(k0 + r) * 512 + n0 + tx];
    }
    __syncthreads();
#pragma unroll
    for (int j = 0; j < 16; j++) {
        const int r = j * 4 + ty;
        dst[(size_t)(n0 + r) * K + k0 + tx] = f2b(t[tx][r]);
    }
}

// bias concat (rowidx gather removed: QKV now computed on unpadded rows)
__global__ void prep_misc_k(const float* bq, const float* bk, const float* bv,
                            const float* bm, const float* blv,
                            float* bqkv, float* bml)
{
    const int i = blockIdx.x * 256 + threadIdx.x;
    if (i < 512) {
        bqkv[i] = bq[i]; bqkv[512 + i] = bk[i]; bqkv[1024 + i] = bv[i];
        bml[i] = bm[i];  bml[512 + i] = blv[i];
    }
}

// one block per sequence. seg_out[b] = (sum_{l<len} attn[l,:]) @ V / len
// qkv is UNPADDED [Nctx x 1536]; sequence rows are consecutive starting at sse[2b].
// Rows l >= len read the next sequence's data but are fully masked out of the math.
__global__ __launch_bounds__(256, 2)
void attn_k(const bf16* __restrict__ qkv, const int* __restrict__ sse, bf16* __restrict__ seg)
{
    __shared__ bf16 qsh[48 * 128];
    __shared__ bf16 ksh[48 * 128];
    __shared__ float ss[48 * 49];
    __shared__ float wbuf[4 * 48];
    __shared__ float wfin[48];

    const int b = blockIdx.x;
    const int tid = threadIdx.x;
    const int wave = tid >> 6, lane = tid & 63;
    const int st  = sse[2 * b];
    const int len = sse[2 * b + 1] - st;
    const size_t rowbase = (size_t)st * 1536;

    int pl[9], pm[9]; float sc[9];
    const int np = len * len;
#pragma unroll
    for (int i = 0; i < 9; i++) {
        const int p = tid + i * 256;
        if (p < np) { pl[i] = p / len; pm[i] = p - pl[i] * len; }
        else pl[i] = -1;
        sc[i] = 0.f;
    }

    int srow[3], scol[3];
#pragma unroll
    for (int j = 0; j < 3; j++) { const int t = j * 256 + tid; srow[j] = t >> 4; scol[j] = t & 15; }

    for (int ch = 0; ch < 4; ch++) {
#pragma unroll
        for (int j = 0; j < 3; j++) {
            const int row = srow[j], c = scol[j];
            const bf16* g = qkv + rowbase + (size_t)row * 1536 + (ch << 7) + (c << 3);
            const int lc = row * 128 + ((c ^ (row & 15)) << 3);   // XOR swizzle vs bank conflicts
            *(bf16x8*)&qsh[lc] = *(const bf16x8*)g;
            *(bf16x8*)&ksh[lc] = *(const bf16x8*)(g + 512);
        }
        __syncthreads();
#pragma unroll
        for (int i = 0; i < 9; i++) {
            if (pl[i] < 0) continue;
            const int l = pl[i], m = pm[i];
            const int lbase = l * 128, mbase = m * 128;
            const int lx = l & 15, mx = m & 15;
            float s0 = 0.f, s1 = 0.f;
#pragma unroll 1
            for (int c8 = 0; c8 < 16; c8++) {
                const bf16x8 qv = *(const bf16x8*)&qsh[lbase + ((c8 ^ lx) << 3)];
                const bf16x8 kv = *(const bf16x8*)&ksh[mbase + ((c8 ^ mx) << 3)];
                const u32x4 qu = __builtin_bit_cast(u32x4, qv);
                const u32x4 ku = __builtin_bit_cast(u32x4, kv);
#pragma unroll
                for (int t = 0; t < 4; t++) {
                    s0 += lo16f(qu[t]) * lo16f(ku[t]);
                    s1 += hi16f(qu[t]) * hi16f(ku[t]);
                }
            }
            sc[i] += s0 + s1;
        }
        __syncthreads();
    }

#pragma unroll
    for (int i = 0; i < 9; i++)
        if (pl[i] >= 0) ss[pl[i] * 49 + pm[i]] = sc[i] * 0.044194173824159216f; // 1/sqrt(512)
    __syncthreads();

    float wacc = 0.f;
    for (int l = wave; l < len; l += 4) {
        const float v = (lane < len) ? ss[l * 49 + lane] : -3.0e38f;
        float mx = v;
#pragma unroll
        for (int o = 32; o; o >>= 1) mx = fmaxf(mx, __shfl_xor(mx, o));
        const float e = (lane < len) ? __expf(v - mx) : 0.f;
        float sm = e;
#pragma unroll
        for (int o = 32; o; o >>= 1) sm += __shfl_xor(sm, o);
        wacc += e / sm;
    }
    if (lane < 48) wbuf[wave * 48 + lane] = wacc;
    __syncthreads();
    if (tid < 48) wfin[tid] = wbuf[tid] + wbuf[48 + tid] + wbuf[96 + tid] + wbuf[144 + tid];
    __syncthreads();

    const int d0 = tid * 2;
    float a0 = 0.f, a1 = 0.f;
    for (int m = 0; m < len; m++) {
        const float wv = wfin[m];
        const unsigned u = *(const unsigned*)(qkv + rowbase + (size_t)m * 1536 + 1024 + d0);
        a0 += wv * lo16f(u);
        a1 += wv * hi16f(u);
    }
    const float inv = 1.f / (float)len;
    seg[(size_t)b * 512 + d0]     = f2b(a0 * inv);
    seg[(size_t)b * 512 + d0 + 1] = f2b(a1 * inv);
}

// z = normalize(mean + exp(0.5 lv)*eps) * sqrt(512); also packs decoder inputs U
__global__ __launch_bounds__(256)
void z_k(const float* __restrict__ meanp, const float* __restrict__ lvp,
         const float* __restrict__ eps, const float* __restrict__ tc, const float* __restrict__ tr,
         float* __restrict__ zoutp, bf16* __restrict__ U)
{
    __shared__ float red[4];
    const int b = blockIdx.x, tid = threadIdx.x;
    const int wave = tid >> 6, lane = tid & 63;
    const int d0 = tid * 2;
    float z0[2];
#pragma unroll
    for (int j = 0; j < 2; j++) {
        const float m = meanp[(size_t)b * 512 + d0 + j];
        const float l = lvp[(size_t)b * 512 + d0 + j];
        const float e = eps[(size_t)b * 512 + d0 + j];
        z0[j] = m + __expf(0.5f * l) * e;
    }
    float ssum = z0[0] * z0[0] + z0[1] * z0[1];
#pragma unroll
    for (int o = 32; o; o >>= 1) ssum += __shfl_xor(ssum, o);
    if (lane == 0) red[wave] = ssum;
    __syncthreads();
    const float tot = red[0] + red[1] + red[2] + red[3];
    float nrm = fmaxf(sqrtf(tot), 1e-12f);
    const float s = 22.627416997969522f / nrm;   // sqrt(512)
#pragma unroll
    for (int j = 0; j < 2; j++) {
        const float z = z0[j] * s;
        zoutp[(size_t)b * 512 + d0 + j] = z;
        const bf16 zb = f2b(z);
        U[(size_t)b * 1536 + 1024 + d0 + j] = zb;
        U[(size_t)(2048 + b) * 1536 + 1024 + d0 + j] = zb;
    }
#pragma unroll
    for (int j = 0; j < 4; j++) {
        const int d = tid + j * 256;
        U[(size_t)b * 1536 + d]          = f2b(tc[(size_t)b * 1024 + d]);
        U[(size_t)(2048 + b) * 1536 + d] = f2b(tr[(size_t)b * 1024 + d]);
    }
}

// final decoder dot: out[r] = D2[r,:] . w3 + b3   (one wave per row)
__global__ __launch_bounds__(256)
void dec3_k(const bf16* __restrict__ D2, const float* __restrict__ w3, const float* __restrict__ b3,
            float* __restrict__ out)
{
    const int gw = (blockIdx.x * 256 + threadIdx.x) >> 6;
    const int lane = threadIdx.x & 63;
    const bf16x8 d = *(const bf16x8*)(D2 + (size_t)gw * 512 + lane * 8);
    const u32x4 du = __builtin_bit_cast(u32x4, d);
    float s = 0.f;
#pragma unroll
    for (int t = 0; t < 4; t++) {
        s += lo16f(du[t]) * w3[lane * 8 + 2 * t];
        s += hi16f(du[t]) * w3[lane * 8 + 2 * t + 1];
    }
#pragma unroll
    for (int o = 32; o; o >>= 1) s += __shfl_xor(s, o);
    if (lane == 0) out[gw] = s + b3[0];
}

extern "C" void kernel_launch(void* const* d_in, const int* in_sizes, int n_in,
                              void* d_out, int out_size, void* d_ws, size_t ws_size,
                              hipStream_t stream)
{
    const float* tc    = (const float*)d_in[0];
    const float* tr    = (const float*)d_in[1];
    const float* cc    = (const float*)d_in[2];
    const float* cr    = (const float*)d_in[3];
    const float* eps   = (const float*)d_in[4];
    const float* pe_w1 = (const float*)d_in[5];
    const float* pe_b1 = (const float*)d_in[6];
    const float* pe_w2 = (const float*)d_in[7];
    const float* pe_b2 = (const float*)d_in[8];
    const float* pe_w3 = (const float*)d_in[9];
    const float* pe_b3 = (const float*)d_in[10];
    const float* wq    = (const float*)d_in[11];
    const float* bq    = (const float*)d_in[12];
    const float* wk    = (const float*)d_in[13];
    const float* bk    = (const float*)d_in[14];
    const float* wv    = (const float*)d_in[15];
    const float* bv    = (const float*)d_in[16];
    const float* wm    = (const float*)d_in[17];
    const float* bm    = (const float*)d_in[18];
    const float* wlv   = (const float*)d_in[19];
    const float* blv   = (const float*)d_in[20];
    const float* d_w1  = (const float*)d_in[21];
    const float* d_b1  = (const float*)d_in[22];
    const float* d_w2  = (const float*)d_in[23];
    const float* d_b2  = (const float*)d_in[24];
    const float* d_w3  = (const float*)d_in[25];
    const float* d_b3  = (const float*)d_in[26];
    const int*   sse   = (const int*)d_in[27];
    const int Nctx = in_sizes[2] / 1024;   // 65536

    uint8_t* wsp = (uint8_t*)d_ws;
    size_t off = 0;
    auto alloc = [&](size_t bytes) -> void* {
        void* p = wsp + off;
        off += (bytes + 255) & ~(size_t)255;
        return p;
    };

    bf16* pe_w1t = (bf16*)alloc((size_t)2048 * 512 * 2);
    bf16* pe_w2t = (bf16*)alloc((size_t)512 * 512 * 2);
    bf16* pe_w3t = (bf16*)alloc((size_t)512 * 512 * 2);
    bf16* wqkvt  = (bf16*)alloc((size_t)1536 * 512 * 2);
    bf16* wmlt   = (bf16*)alloc((size_t)1024 * 512 * 2);
    bf16* d_w1t  = (bf16*)alloc((size_t)512 * 1536 * 2);
    bf16* d_w2t  = (bf16*)alloc((size_t)512 * 512 * 2);
    float* bqkv  = (float*)alloc(1536 * 4);
    float* bml   = (float*)alloc(1024 * 4);
    bf16* seg    = (bf16*)alloc((size_t)2048 * 512 * 2);
    bf16* U      = (bf16*)alloc((size_t)4096 * 1536 * 2);
    bf16* D1     = (bf16*)alloc((size_t)4096 * 512 * 2);
    bf16* D2     = (bf16*)alloc((size_t)4096 * 512 * 2);
    bf16* hbuf   = (bf16*)alloc((size_t)Nctx * 512 * 2);            // h1, then pair_embed
    bf16* bigbuf = (bf16*)alloc((size_t)Nctx * 1536 * 2);           // h2, then qkv (unpadded)
    bf16* h1  = hbuf;
    bf16* h2  = bigbuf;
    bf16* peb = hbuf;
    bf16* qkv = bigbuf;

    float* outp  = (float*)d_out;
    float* meanp = outp + 4096;
    float* lvp   = outp + 4096 + 2048 * 512;
    float* zoutp = outp + 4096 + 2 * 2048 * 512;

    // --- prep: weight transposes (fp32 -> bf16 [N x K]), biases
    TP8 tp;
    tp.s[0] = pe_w2; tp.d[0] = pe_w2t;
    tp.s[1] = pe_w3; tp.d[1] = pe_w3t;
    tp.s[2] = wq;    tp.d[2] = wqkvt;
    tp.s[3] = wk;    tp.d[3] = wqkvt + 512 * 512;
    tp.s[4] = wv;    tp.d[4] = wqkvt + 1024 * 512;
    tp.s[5] = wm;    tp.d[5] = wmlt;
    tp.s[6] = wlv;   tp.d[6] = wmlt + 512 * 512;
    tp.s[7] = d_w2;  tp.d[7] = d_w2t;
    transpose8_k<<<dim3(8, 8, 8), 256, 0, stream>>>(tp);
    transpose_g_k<<<dim3(32, 8), 256, 0, stream>>>(pe_w1, pe_w1t, 2048);
    transpose_g_k<<<dim3(24, 8), 256, 0, stream>>>(d_w1, d_w1t, 1536);
    prep_misc_k<<<2, 256, 0, stream>>>(bq, bk, bv, bm, blv, bqkv, bml);

    // --- pair encoder
    gemm_k<1, 1, 0><<<dim3(4, Nctx / 128), 256, 0, stream>>>(cc, cr, pe_w1t, pe_b1, h1, nullptr, Nctx, 512, 2048, 1024);
    gemm_k<0, 1, 0><<<dim3(4, Nctx / 128), 256, 0, stream>>>(h1, nullptr, pe_w2t, pe_b2, h2, nullptr, Nctx, 512, 512, 512);
    gemm_k<0, 0, 0><<<dim3(4, Nctx / 128), 256, 0, stream>>>(h2, nullptr, pe_w3t, pe_b3, peb, nullptr, Nctx, 512, 512, 512);

    // --- QKV projection on UNPADDED rows (sequences are consecutive rows of peb)
    gemm_k<0, 0, 0><<<dim3(12, Nctx / 128), 256, 0, stream>>>(peb, nullptr, wqkvt, bqkv, qkv, nullptr, Nctx, 1536, 512, 512);

    // --- attention + masked mean pool (indexes qkv by sse[2b] directly)
    attn_k<<<2048, 256, 0, stream>>>(qkv, sse, seg);

    // --- latent head: mean / log_var (clipped, fp32 straight to d_out)
    gemm_k<0, 2, 1><<<dim3(8, 16), 256, 0, stream>>>(seg, nullptr, wmlt, bml, meanp, lvp, 2048, 1024, 512, 512);

    // --- z + decoder input packing
    z_k<<<2048, 256, 0, stream>>>(meanp, lvp, eps, tc, tr, zoutp, U);

    // --- decoder (both targets stacked: rows 0..2047 chosen, 2048..4095 rejected)
    gemm_k<0, 1, 0><<<dim3(4, 32), 256, 0, stream>>>(U, nullptr, d_w1t, d_b1, D1, nullptr, 4096, 512, 1536, 1536);
    gemm_k<0, 1, 0><<<dim3(4, 32), 256, 0, stream>>>(D1, nullptr, d_w2t, d_b2, D2, nullptr, 4096, 512, 512, 512);
    dec3_k<<<1024, 256, 0, stream>>>(D2, d_w3, d_b3, outp);

    (void)n_in; (void)out_size; (void)ws_size; (void)in_sizes;
}